// Round 19
// baseline (598.138 us; speedup 1.0000x reference)
//
#include <hip/hip_runtime.h>
#include <hip/hip_fp16.h>
#include <stdint.h>

typedef _Float16 f16;
typedef _Float16 f16x2 __attribute__((ext_vector_type(2)));
typedef _Float16 f16x4 __attribute__((ext_vector_type(4)));
typedef _Float16 f16x8 __attribute__((ext_vector_type(8)));
typedef __fp16 fp16x2 __attribute__((ext_vector_type(2)));  // cvt_pkrtz return type
typedef float f32x4 __attribute__((ext_vector_type(4)));

#define NB 8
#define NL 2048
#define ND 256
#define QKV_ELEMS (NB * NL * ND)   // 4194304

__device__ __forceinline__ f32x4 mfma16(f16x8 a, f16x8 b, f32x4 c) {
  return __builtin_amdgcn_mfma_f32_16x16x32_f16(a, b, c, 0, 0, 0);
}

// ---------------- K0: transpose+convert weights: WT[m][n][k] = (f16)W_m[k][n]
__global__ void k0_wt(const float* __restrict__ Wq, const float* __restrict__ Wk,
                      const float* __restrict__ Wv, f16* __restrict__ WT) {
  int id = blockIdx.x * 256 + threadIdx.x;  // 0..196607
  int m = id >> 16;
  int r = id & 65535;
  int k = r >> 8, n = r & 255;
  const float* W = (m == 0) ? Wq : (m == 1) ? Wk : Wv;
  WT[m * 65536 + n * 256 + k] = (f16)W[k * 256 + n];
}

// ---------------- K1: projections (fp32 A, f16 MFMA, f16 out). 64 rows/block.
// (256,2): r18 win -- caps VGPR at 128 (fits) vs ~168 single-arg.
__global__ __launch_bounds__(256, 2) void k1_proj(
    const float* __restrict__ Aq, const float* __restrict__ Ak, const float* __restrict__ Av,
    const f16* __restrict__ WT, f16* __restrict__ Qh, f16* __restrict__ Kh,
    f16* __restrict__ Vh) {
  const int m = blockIdx.y;
  const float* A = (m == 0) ? Aq : (m == 1) ? Ak : Av;
  f16* O = (m == 0) ? Qh : (m == 1) ? Kh : Vh;
  const f16* Wm = WT + m * 65536;
  const int row0 = blockIdx.x * 64;
  const int tid = threadIdx.x;
  const int lane = tid & 63, w = tid >> 6;

  __shared__ f16 Ald[64 * 64];    // [r][k], swizzled ((r&7)<<4) on byte offset
  __shared__ f16 Wld[256 * 64];   // [n][k], swizzled ((n&7)<<4)

  f32x4 acc[16];
#pragma unroll
  for (int i = 0; i < 16; ++i) acc[i] = f32x4{0.f, 0.f, 0.f, 0.f};

  for (int kb = 0; kb < 4; ++kb) {
    __syncthreads();
    {  // stage A tile 64x64 fp32 -> f16
      const int r = tid >> 2, c0 = (tid & 3) * 16;
      const float* src = A + (size_t)(row0 + r) * ND + kb * 64 + c0;
      f16x8 h0, h1;
#pragma unroll
      for (int j = 0; j < 8; ++j) h0[j] = (f16)src[j];
#pragma unroll
      for (int j = 0; j < 8; ++j) h1[j] = (f16)src[8 + j];
      const int sw = (r & 7) << 4;
      *(f16x8*)((char*)Ald + r * 128 + ((c0 * 2) ^ sw)) = h0;
      *(f16x8*)((char*)Ald + r * 128 + ((c0 * 2 + 16) ^ sw)) = h1;
    }
    {  // stage WT tile [256][64] f16
      const int n = tid;
      const f16* src = Wm + n * 256 + kb * 64;
      const int sw = (n & 7) << 4;
#pragma unroll
      for (int j = 0; j < 8; ++j) {
        f16x8 v = *(const f16x8*)(src + j * 8);
        *(f16x8*)((char*)Wld + n * 128 + ((j * 16) ^ sw)) = v;
      }
    }
    __syncthreads();
#pragma unroll
    for (int kk = 0; kk < 2; ++kk) {
      const int arow = w * 16 + (lane & 15);
      const int ko = kk * 64 + (lane >> 4) * 16;
      f16x8 a = *(const f16x8*)((char*)Ald + arow * 128 + (ko ^ ((arow & 7) << 4)));
#pragma unroll
      for (int nt = 0; nt < 16; ++nt) {
        const int n = nt * 16 + (lane & 15);
        f16x8 b = *(const f16x8*)((char*)Wld + n * 128 + (ko ^ ((n & 7) << 4)));
        acc[nt] = mfma16(a, b, acc[nt]);
      }
    }
  }
  const int rl = (lane >> 4) * 4;
#pragma unroll
  for (int nt = 0; nt < 16; ++nt) {
    const int col = nt * 16 + (lane & 15);
#pragma unroll
    for (int j = 0; j < 4; ++j)
      O[(size_t)(row0 + w * 16 + rl + j) * ND + col] = (f16)acc[nt][j];
  }
}

// ---------------- K2: Srel[b] = skew(Q[b] @ (K[b]-Q[b])^T), 128x128 tile.
// E = K - Q computed during B-tile staging. Epilogue writes each QE element
// DIRECTLY to its skew target (bijection); only Srel[q][q+1] stays unwritten
// (the zero column; masked in k3). (256,2): r18 win.
__global__ __launch_bounds__(256, 2) void k2_qe(const f16* __restrict__ Qh,
                                                const f16* __restrict__ Kh,
                                                f16* __restrict__ QEh) {
  const int b = blockIdx.z;
  const int m0 = blockIdx.x * 128, n0 = blockIdx.y * 128;
  const int tid = threadIdx.x, lane = tid & 63, w = tid >> 6;
  const int wr = (w >> 1) * 64, wc = (w & 1) * 64;
  const f16* Qb = Qh + (size_t)b * NL * ND;
  const f16* Kb = Kh + (size_t)b * NL * ND;

  __shared__ f16 As[128 * 64];  // [r][k] swizzled ((r&7)<<4)
  __shared__ f16 Bs[128 * 64];

  f32x4 acc[4][4];
#pragma unroll
  for (int i = 0; i < 4; ++i)
#pragma unroll
    for (int j = 0; j < 4; ++j) acc[i][j] = f32x4{0.f, 0.f, 0.f, 0.f};

  for (int kb = 0; kb < 4; ++kb) {
    __syncthreads();
#pragma unroll
    for (int j = 0; j < 4; ++j) {
      const int c = j * 256 + tid;       // 1024 chunks of 16B
      const int r = c >> 3;
      const int ko = (c & 7) * 16;       // byte offset in row
      const int sw = (r & 7) << 4;
      f16x8 va = *(const f16x8*)((const char*)(Qb + (size_t)(m0 + r) * ND + kb * 64) + ko);
      *(f16x8*)((char*)As + r * 128 + (ko ^ sw)) = va;
      f16x8 vk = *(const f16x8*)((const char*)(Kb + (size_t)(n0 + r) * ND + kb * 64) + ko);
      f16x8 vq = *(const f16x8*)((const char*)(Qb + (size_t)(n0 + r) * ND + kb * 64) + ko);
      *(f16x8*)((char*)Bs + r * 128 + (ko ^ sw)) = vk - vq;  // E = K - Q
    }
    __syncthreads();
#pragma unroll
    for (int kk = 0; kk < 2; ++kk) {
      const int ko = kk * 64 + (lane >> 4) * 16;
      f16x8 a[4], bf[4];
#pragma unroll
      for (int mt = 0; mt < 4; ++mt) {
        const int r = wr + mt * 16 + (lane & 15);
        a[mt] = *(const f16x8*)((char*)As + r * 128 + (ko ^ ((r & 7) << 4)));
      }
#pragma unroll
      for (int nt = 0; nt < 4; ++nt) {
        const int r = wc + nt * 16 + (lane & 15);
        bf[nt] = *(const f16x8*)((char*)Bs + r * 128 + (ko ^ ((r & 7) << 4)));
      }
#pragma unroll
      for (int mt = 0; mt < 4; ++mt)
#pragma unroll
        for (int nt = 0; nt < 4; ++nt) acc[mt][nt] = mfma16(a[mt], bf[nt], acc[mt][nt]);
    }
  }
  f16* outb = QEh + (size_t)b * NL * NL;
#pragma unroll
  for (int mt = 0; mt < 4; ++mt)
#pragma unroll
    for (int nt = 0; nt < 4; ++nt) {
      const int col = n0 + wc + nt * 16 + (lane & 15);
#pragma unroll
      for (int j = 0; j < 4; ++j) {
        const int row = m0 + wr + mt * 16 + (lane >> 4) * 4 + j;
        int qrow, kk2;
        if (col >= (NL - 1) - row) { qrow = row; kk2 = col + row - (NL - 1); }
        else { qrow = row - 1; kk2 = col + row + 1; }
        if (qrow >= 0)
          outb[(size_t)qrow * NL + kk2] = (f16)acc[mt][nt][j];
      }
    }
}

// ---------------- K3p: 4-way key-split flash attention partials.
// SINGLE-buffer K/V (36.9 KB -> 4 blocks/CU by LDS) + skewed-Srel gather.
// Occupancy experiment: amdgpu_waves_per_eu(4,8) -- min 4 waves/EU targets
// VGPR<=128 (proven fit), max 8 leaves residency to resources. The 2-arg
// launch_bounds form appeared to pin waves/EU min=max (r8: 21% occupancy
// despite 4 blocks/CU fitting); this attribute separates min from max.
#define KVBUF 36864   // 16384 (K [32][256] swz) + 20480 (V [256][40])
#define NITP 16
__global__ __launch_bounds__(256)
__attribute__((amdgpu_waves_per_eu(4, 8))) void k3_part(
    const f16* __restrict__ Qh, const f16* __restrict__ Kh, const f16* __restrict__ Vh,
    const f16* __restrict__ QEh, f16* __restrict__ Pac, float* __restrict__ Pml) {
  __shared__ char smem[KVBUF];
  const int b = blockIdx.y;
  const int g = blockIdx.z;
  const int q0 = blockIdx.x * 64;
  const int tid = threadIdx.x, lane = tid & 63, w = tid >> 6;
  const int qw = q0 + w * 16;
  const int gi = lane >> 4;

  const f16* Qb = Qh + (size_t)b * NL * ND;
  const f16* Kb = Kh + (size_t)b * NL * ND;
  const f16* Vb = Vh + (size_t)b * NL * ND;
  const f16* QEb = QEh + (size_t)b * NL * NL;  // skewed Srel layout

  f16x8 qf[8];
  {
    const int r = qw + (lane & 15);
#pragma unroll
    for (int kk = 0; kk < 8; ++kk)
      qf[kk] = *(const f16x8*)(Qb + (size_t)r * ND + kk * 32 + gi * 8);
  }

  f32x4 acc[16];
#pragma unroll
  for (int i = 0; i < 16; ++i) acc[i] = f32x4{0.f, 0.f, 0.f, 0.f};
  float mrun = -1e30f, lrun = 0.f;

  f16x8 kst[4], vst[4];
  const int kp = tid & 15, dch = tid >> 4;

  auto stage_load = [&](int t) {
    const f16* Ks = Kb + (size_t)(g * NITP + t) * 32 * ND;
#pragma unroll
    for (int j = 0; j < 4; ++j) {
      const int c = j * 256 + tid;
      kst[j] = *(const f16x8*)(Ks + (c >> 5) * ND + (c & 31) * 8);
    }
    const f16* Vs = Vb + (size_t)(g * NITP + t) * 32 * ND;
    vst[0] = *(const f16x8*)(Vs + (2 * kp) * ND + dch * 16);
    vst[1] = *(const f16x8*)(Vs + (2 * kp) * ND + dch * 16 + 8);
    vst[2] = *(const f16x8*)(Vs + (2 * kp + 1) * ND + dch * 16);
    vst[3] = *(const f16x8*)(Vs + (2 * kp + 1) * ND + dch * 16 + 8);
  };
  auto stage_write = [&]() {
    char* Kld = smem;
    char* Vld = smem + 16384;
#pragma unroll
    for (int j = 0; j < 4; ++j) {
      const int c = j * 256 + tid;
      const int key = c >> 5, d0 = (c & 31) * 16;
      *(f16x8*)(Kld + key * 512 + (d0 ^ ((key & 7) << 4))) = kst[j];
    }
#pragma unroll
    for (int jj = 0; jj < 16; ++jj) {
      f16x2 pr;
      pr.x = (jj < 8) ? vst[0][jj & 7] : vst[1][jj & 7];  // key 2*kp
      pr.y = (jj < 8) ? vst[2][jj & 7] : vst[3][jj & 7];  // key 2*kp+1
      *(f16x2*)(Vld + (dch * 16 + jj) * 80 + kp * 4) = pr;
    }
  };

  stage_load(0);
  stage_write();
  __syncthreads();

  const int qa = qw + (lane & 15);

  for (int t = 0; t < NITP; ++t) {
    const int k0 = (g * NITP + t) * 32;

    // srel gather: ROW-CONTIGUOUS from skewed Srel (2 vector loads/lane)
    float srel[2][4];
#pragma unroll
    for (int nt = 0; nt < 2; ++nt) {
      const int kb2 = k0 + nt * 16 + gi * 4;
      f16x4 v4 = *(const f16x4*)(QEb + (size_t)qa * NL + kb2);
#pragma unroll
      for (int j = 0; j < 4; ++j)
        srel[nt][j] = (kb2 + j == qa + 1) ? 0.f : (float)v4[j];
    }

    if (t < NITP - 1) stage_load(t + 1);

    const char* Kld = smem;
    const char* Vld = smem + 16384;

    f32x4 s[2] = {f32x4{0.f, 0.f, 0.f, 0.f}, f32x4{0.f, 0.f, 0.f, 0.f}};
#pragma unroll
    for (int kk = 0; kk < 8; ++kk) {
      const int ko = kk * 64 + gi * 16;
#pragma unroll
      for (int nt = 0; nt < 2; ++nt) {
        const int key = nt * 16 + (lane & 15);
        f16x8 af = *(const f16x8*)(Kld + key * 512 + (ko ^ ((key & 7) << 4)));
        s[nt] = mfma16(af, qf[kk], s[nt]);
      }
    }

    float sv[2][4];
#pragma unroll
    for (int nt = 0; nt < 2; ++nt)
#pragma unroll
      for (int j = 0; j < 4; ++j) sv[nt][j] = 0.0625f * (s[nt][j] + srel[nt][j]);

    float pm = fmaxf(fmaxf(fmaxf(sv[0][0], sv[0][1]), fmaxf(sv[0][2], sv[0][3])),
                     fmaxf(fmaxf(sv[1][0], sv[1][1]), fmaxf(sv[1][2], sv[1][3])));
    pm = fmaxf(pm, __shfl_xor(pm, 16, 64));
    pm = fmaxf(pm, __shfl_xor(pm, 32, 64));

    float p[2][4];
    if (__any(pm > mrun + 8.f)) {
      const float mn = fmaxf(mrun, pm);
      const float al = __expf(mrun - mn);
      mrun = mn;
#pragma unroll
      for (int nt = 0; nt < 2; ++nt)
#pragma unroll
        for (int j = 0; j < 4; ++j) p[nt][j] = __expf(sv[nt][j] - mrun);
      float rs = (p[0][0] + p[0][1]) + (p[0][2] + p[0][3]) +
                 (p[1][0] + p[1][1]) + (p[1][2] + p[1][3]);
      rs += __shfl_xor(rs, 16, 64);
      rs += __shfl_xor(rs, 32, 64);
      lrun = lrun * al + rs;
#pragma unroll
      for (int j = 0; j < 4; ++j) {
        const float aj = __shfl(al, gi * 4 + j, 16);
#pragma unroll
        for (int dt = 0; dt < 16; ++dt) acc[dt][j] *= aj;
      }
    } else {
#pragma unroll
      for (int nt = 0; nt < 2; ++nt)
#pragma unroll
        for (int j = 0; j < 4; ++j) p[nt][j] = __expf(sv[nt][j] - mrun);
      float rs = (p[0][0] + p[0][1]) + (p[0][2] + p[0][3]) +
                 (p[1][0] + p[1][1]) + (p[1][2] + p[1][3]);
      rs += __shfl_xor(rs, 16, 64);
      rs += __shfl_xor(rs, 32, 64);
      lrun += rs;
    }

    union {
      fp16x2 h2[2];
      f16x4 h4;
    } pu0, pu1;
    pu0.h2[0] = __builtin_amdgcn_cvt_pkrtz(p[0][0], p[0][1]);
    pu0.h2[1] = __builtin_amdgcn_cvt_pkrtz(p[0][2], p[0][3]);
    pu1.h2[0] = __builtin_amdgcn_cvt_pkrtz(p[1][0], p[1][1]);
    pu1.h2[1] = __builtin_amdgcn_cvt_pkrtz(p[1][2], p[1][3]);

#pragma unroll
    for (int dt = 0; dt < 16; ++dt) {
      const char* vrow = Vld + (dt * 16 + (lane & 15)) * 80 + 8 * gi;
      f16x4 v0 = *(const f16x4*)(vrow);
      f16x4 v1 = *(const f16x4*)(vrow + 32);
      acc[dt] = __builtin_amdgcn_mfma_f32_16x16x16f16(pu0.h4, v0, acc[dt], 0, 0, 0);
      acc[dt] = __builtin_amdgcn_mfma_f32_16x16x16f16(pu1.h4, v1, acc[dt], 0, 0, 0);
    }

    __syncthreads();
    if (t < NITP - 1) stage_write();
    __syncthreads();
  }

  // ---- write l-normalized partials (f16) ----
  const float inv = 1.f / lrun;
  f16* Pb = Pac + ((size_t)g * (NB * NL) + (size_t)b * NL) * ND;
#pragma unroll
  for (int j = 0; j < 4; ++j) {
    const float invj = __shfl(inv, gi * 4 + j, 16);
    const int row = qw + gi * 4 + j;
#pragma unroll
    for (int dt = 0; dt < 16; ++dt)
      Pb[(size_t)row * ND + dt * 16 + (lane & 15)] = (f16)(acc[dt][j] * invj);
  }
  if (lane < 16) {
    const size_t r = (size_t)g * (NB * NL) + (size_t)b * NL + qw + lane;
    Pml[r * 2 + 0] = mrun;
    Pml[r * 2 + 1] = lrun;
  }
}

// ---------------- K4: combine 4 key-group normalized partials -> output
__global__ __launch_bounds__(256) void k4_comb(const f16* __restrict__ Pac,
                                               const float* __restrict__ Pml,
                                               float* __restrict__ Out) {
  const int row = blockIdx.x * 4 + (threadIdx.x >> 6);
  const int lane = threadIdx.x & 63;
  float m[4], l[4];
#pragma unroll
  for (int gq = 0; gq < 4; ++gq) {
    const size_t r = (size_t)gq * (NB * NL) + row;
    m[gq] = Pml[r * 2 + 0];
    l[gq] = Pml[r * 2 + 1];
  }
  const float M = fmaxf(fmaxf(m[0], m[1]), fmaxf(m[2], m[3]));
  float wgt[4];
  float denom = 0.f;
#pragma unroll
  for (int gq = 0; gq < 4; ++gq) {
    wgt[gq] = l[gq] * __expf(m[gq] - M);
    denom += wgt[gq];
  }
  const float inv = 1.f / denom;
  const size_t base = (size_t)row * ND + lane * 4;
  float o[4] = {0.f, 0.f, 0.f, 0.f};
#pragma unroll
  for (int gq = 0; gq < 4; ++gq) {
    f16x4 p = *(const f16x4*)(Pac + (size_t)gq * (NB * NL) * ND + base);
    const float s = wgt[gq] * inv;
#pragma unroll
    for (int e = 0; e < 4; ++e) o[e] += (float)p[e] * s;
  }
  f32x4 ov = {o[0], o[1], o[2], o[3]};
  *(f32x4*)(Out + base) = ov;
}

// ---------------- K3 fallback (r6 form, skewed-Srel gather), for small ws.
#define NIT 32
__global__ __launch_bounds__(512, 2) void k3_attn(
    const f16* __restrict__ Qh, const f16* __restrict__ Kh, const f16* __restrict__ Vh,
    const f16* __restrict__ QEh, float* __restrict__ Out) {
  extern __shared__ char smemd[];  // 73728 B
  const int b = blockIdx.y;
  const int q0 = blockIdx.x * 64;
  const int tid = threadIdx.x, lane = tid & 63, w = tid >> 6;
  const int g = w >> 2, wq = w & 3;
  const int qw = q0 + wq * 16;
  const int lt = tid & 255;
  const int gi = lane >> 4;

  float* Cst = (float*)smemd;
  float* ml = (float*)(smemd + 65536);

  const f16* Qb = Qh + (size_t)b * NL * ND;
  const f16* Kb = Kh + (size_t)b * NL * ND;
  const f16* Vb = Vh + (size_t)b * NL * ND;
  const f16* QEb = QEh + (size_t)b * NL * NL;  // skewed Srel layout

  f16x8 qf[8];
  {
    const int r = qw + (lane & 15);
#pragma unroll
    for (int kk = 0; kk < 8; ++kk)
      qf[kk] = *(const f16x8*)(Qb + (size_t)r * ND + kk * 32 + gi * 8);
  }

  f32x4 acc[16];
#pragma unroll
  for (int i = 0; i < 16; ++i) acc[i] = f32x4{0.f, 0.f, 0.f, 0.f};
  float mrun = -1e30f, lrun = 0.f;

  f16x8 kst[4], vst[4];
  const int kp = lt & 15, dch = lt >> 4;

  auto stage_load = [&](int t) {
    const f16* Ks = Kb + (size_t)(g * NIT + t) * 32 * ND;
#pragma unroll
    for (int j = 0; j < 4; ++j) {
      const int c = j * 256 + lt;
      kst[j] = *(const f16x8*)(Ks + (c >> 5) * ND + (c & 31) * 8);
    }
    const f16* Vs = Vb + (size_t)(g * NIT + t) * 32 * ND;
    vst[0] = *(const f16x8*)(Vs + (2 * kp) * ND + dch * 16);
    vst[1] = *(const f16x8*)(Vs + (2 * kp) * ND + dch * 16 + 8);
    vst[2] = *(const f16x8*)(Vs + (2 * kp + 1) * ND + dch * 16);
    vst[3] = *(const f16x8*)(Vs + (2 * kp + 1) * ND + dch * 16 + 8);
  };
  auto stage_write = [&]() {
    char* Kld = smemd + g * KVBUF;
    char* Vld = Kld + 16384;
#pragma unroll
    for (int j = 0; j < 4; ++j) {
      const int c = j * 256 + lt;
      const int key = c >> 5, d0 = (c & 31) * 16;
      *(f16x8*)(Kld + key * 512 + (d0 ^ ((key & 7) << 4))) = kst[j];
    }
#pragma unroll
    for (int jj = 0; jj < 16; ++jj) {
      f16x2 pr;
      pr.x = (jj < 8) ? vst[0][jj & 7] : vst[1][jj & 7];
      pr.y = (jj < 8) ? vst[2][jj & 7] : vst[3][jj & 7];
      *(f16x2*)(Vld + (dch * 16 + jj) * 80 + kp * 4) = pr;
    }
  };

  stage_load(0);
  stage_write();
  __syncthreads();

  const int qa = qw + (lane & 15);

  for (int t = 0; t < NIT; ++t) {
    const int k0 = (g * NIT + t) * 32;

    float srel[2][4];
#pragma unroll
    for (int nt = 0; nt < 2; ++nt) {
      const int kb2 = k0 + nt * 16 + gi * 4;
      f16x4 v4 = *(const f16x4*)(QEb + (size_t)qa * NL + kb2);
#pragma unroll
      for (int j = 0; j < 4; ++j)
        srel[nt][j] = (kb2 + j == qa + 1) ? 0.f : (float)v4[j];
    }

    if (t < NIT - 1) stage_load(t + 1);

    const char* Kld = smemd + g * KVBUF;
    const char* Vld = Kld + 16384;

    f32x4 s[2] = {f32x4{0.f, 0.f, 0.f, 0.f}, f32x4{0.f, 0.f, 0.f, 0.f}};
#pragma unroll
    for (int kk = 0; kk < 8; ++kk) {
      const int ko = kk * 64 + gi * 16;
#pragma unroll
      for (int nt = 0; nt < 2; ++nt) {
        const int key = nt * 16 + (lane & 15);
        f16x8 af = *(const f16x8*)(Kld + key * 512 + (ko ^ ((key & 7) << 4)));
        s[nt] = mfma16(af, qf[kk], s[nt]);
      }
    }

    float sv[2][4];
#pragma unroll
    for (int nt = 0; nt < 2; ++nt)
#pragma unroll
      for (int j = 0; j < 4; ++j) sv[nt][j] = 0.0625f * (s[nt][j] + srel[nt][j]);

    float pm = fmaxf(fmaxf(fmaxf(sv[0][0], sv[0][1]), fmaxf(sv[0][2], sv[0][3])),
                     fmaxf(fmaxf(sv[1][0], sv[1][1]), fmaxf(sv[1][2], sv[1][3])));
    pm = fmaxf(pm, __shfl_xor(pm, 16, 64));
    pm = fmaxf(pm, __shfl_xor(pm, 32, 64));

    float p[2][4];
    if (__any(pm > mrun + 8.f)) {
      const float mn = fmaxf(mrun, pm);
      const float al = __expf(mrun - mn);
      mrun = mn;
#pragma unroll
      for (int nt = 0; nt < 2; ++nt)
#pragma unroll
        for (int j = 0; j < 4; ++j) p[nt][j] = __expf(sv[nt][j] - mrun);
      float rs = (p[0][0] + p[0][1]) + (p[0][2] + p[0][3]) +
                 (p[1][0] + p[1][1]) + (p[1][2] + p[1][3]);
      rs += __shfl_xor(rs, 16, 64);
      rs += __shfl_xor(rs, 32, 64);
      lrun = lrun * al + rs;
#pragma unroll
      for (int j = 0; j < 4; ++j) {
        const float aj = __shfl(al, gi * 4 + j, 16);
#pragma unroll
        for (int dt = 0; dt < 16; ++dt) acc[dt][j] *= aj;
      }
    } else {
#pragma unroll
      for (int nt = 0; nt < 2; ++nt)
#pragma unroll
        for (int j = 0; j < 4; ++j) p[nt][j] = __expf(sv[nt][j] - mrun);
      float rs = (p[0][0] + p[0][1]) + (p[0][2] + p[0][3]) +
                 (p[1][0] + p[1][1]) + (p[1][2] + p[1][3]);
      rs += __shfl_xor(rs, 16, 64);
      rs += __shfl_xor(rs, 32, 64);
      lrun += rs;
    }

    union {
      fp16x2 h2[2];
      f16x4 h4;
    } pu0, pu1;
    pu0.h2[0] = __builtin_amdgcn_cvt_pkrtz(p[0][0], p[0][1]);
    pu0.h2[1] = __builtin_amdgcn_cvt_pkrtz(p[0][2], p[0][3]);
    pu1.h2[0] = __builtin_amdgcn_cvt_pkrtz(p[1][0], p[1][1]);
    pu1.h2[1] = __builtin_amdgcn_cvt_pkrtz(p[1][2], p[1][3]);

#pragma unroll
    for (int dt = 0; dt < 16; ++dt) {
      const char* vrow = Vld + (dt * 16 + (lane & 15)) * 80 + 8 * gi;
      f16x4 v0 = *(const f16x4*)(vrow);
      f16x4 v1 = *(const f16x4*)(vrow + 32);
      acc[dt] = __builtin_amdgcn_mfma_f32_16x16x16f16(pu0.h4, v0, acc[dt], 0, 0, 0);
      acc[dt] = __builtin_amdgcn_mfma_f32_16x16x16f16(pu1.h4, v1, acc[dt], 0, 0, 0);
    }

    __syncthreads();
    if (t < NIT - 1) stage_write();
    __syncthreads();
  }

  if (g == 1) {
#pragma unroll
    for (int dt = 0; dt < 16; ++dt)
#pragma unroll
      for (int j = 0; j < 4; ++j)
        Cst[wq * 4096 + (gi * 4 + j) * 256 + dt * 16 + (lane & 15)] = acc[dt][j];
    if (lane < 16) {
      ml[(wq * 16 + lane) * 2 + 0] = mrun;
      ml[(wq * 16 + lane) * 2 + 1] = lrun;
    }
  }
  __syncthreads();
  if (g == 0) {
    float* Ob = Out + (size_t)b * NL * ND;
#pragma unroll
    for (int j = 0; j < 4; ++j) {
      const int rloc = gi * 4 + j;
      const float m0r = __shfl(mrun, rloc, 16);
      const float l0r = __shfl(lrun, rloc, 16);
      const float m1 = ml[(wq * 16 + rloc) * 2 + 0];
      const float l1 = ml[(wq * 16 + rloc) * 2 + 1];
      const float M = fmaxf(m0r, m1);
      const float c0 = __expf(m0r - M), c1 = __expf(m1 - M);
      const float inv = 1.f / (l0r * c0 + l1 * c1);
      const int row = qw + rloc;
#pragma unroll
      for (int dt = 0; dt < 16; ++dt) {
        const float o1 = Cst[wq * 4096 + rloc * 256 + dt * 16 + (lane & 15)];
        Ob[(size_t)row * ND + dt * 16 + (lane & 15)] = (acc[dt][j] * c0 + o1 * c1) * inv;
      }
    }
  }
}

extern "C" void kernel_launch(void* const* d_in, const int* in_sizes, int n_in,
                              void* d_out, int out_size, void* d_ws, size_t ws_size,
                              hipStream_t stream) {
  (void)in_sizes; (void)n_in; (void)out_size;
  const float* inQ = (const float*)d_in[0];
  const float* inK = (const float*)d_in[1];
  const float* inV = (const float*)d_in[2];
  const float* Wq = (const float*)d_in[3];
  const float* Wk = (const float*)d_in[4];
  const float* Wv = (const float*)d_in[5];
  float* out = (float*)d_out;

  // ws layout (f16): Qh,Kh,Vh [B*L*D]; WT [3*256*256]; QEh [B*L*L] (SKEWED);
  // Pac f16 [4][B*L][D]; then (f32) Pml [4][B*L][2].
  f16* ws = (f16*)d_ws;
  f16* Qh = ws;
  f16* Kh = Qh + (size_t)QKV_ELEMS;
  f16* Vh = Kh + (size_t)QKV_ELEMS;
  f16* WT = Vh + (size_t)QKV_ELEMS;
  f16* QEh = WT + 3 * 65536;
  f16* Pac = QEh + (size_t)NB * NL * NL;
  float* Pml = (float*)(Pac + (size_t)4 * QKV_ELEMS);
  const size_t need = (size_t)((char*)(Pml + 4 * NB * NL * 2) - (char*)d_ws);

  k0_wt<<<dim3(768), dim3(256), 0, stream>>>(Wq, Wk, Wv, WT);
  k1_proj<<<dim3(256, 3), dim3(256), 0, stream>>>(inQ, inK, inV, WT, Qh, Kh, Vh);
  k2_qe<<<dim3(16, 16, 8), dim3(256), 0, stream>>>(Qh, Kh, QEh);
  if (ws_size >= need) {
    k3_part<<<dim3(32, 8, 4), dim3(256), 0, stream>>>(Qh, Kh, Vh, QEh, Pac, Pml);
    k4_comb<<<dim3(NB * NL / 4), dim3(256), 0, stream>>>(Pac, Pml, out);
  } else {
    k3_attn<<<dim3(32, 8), dim3(512), 73728, stream>>>(Qh, Kh, Vh, QEh, out);
  }
}

// Round 20
// 164.605 us; speedup vs baseline: 3.6338x; 3.6338x over previous
//
#include <hip/hip_runtime.h>
#include <hip/hip_fp16.h>
#include <stdint.h>

typedef _Float16 f16;
typedef _Float16 f16x2 __attribute__((ext_vector_type(2)));
typedef _Float16 f16x4 __attribute__((ext_vector_type(4)));
typedef _Float16 f16x8 __attribute__((ext_vector_type(8)));
typedef __fp16 fp16x2 __attribute__((ext_vector_type(2)));  // cvt_pkrtz return type
typedef float f32x4 __attribute__((ext_vector_type(4)));

#define NB 8
#define NL 2048
#define ND 256
#define QKV_ELEMS (NB * NL * ND)   // 4194304

__device__ __forceinline__ f32x4 mfma16(f16x8 a, f16x8 b, f32x4 c) {
  return __builtin_amdgcn_mfma_f32_16x16x32_f16(a, b, c, 0, 0, 0);
}

// ---------------- K0: transpose+convert weights: WT[m][n][k] = (f16)W_m[k][n]
__global__ void k0_wt(const float* __restrict__ Wq, const float* __restrict__ Wk,
                      const float* __restrict__ Wv, f16* __restrict__ WT) {
  int id = blockIdx.x * 256 + threadIdx.x;  // 0..196607
  int m = id >> 16;
  int r = id & 65535;
  int k = r >> 8, n = r & 255;
  const float* W = (m == 0) ? Wq : (m == 1) ? Wk : Wv;
  WT[m * 65536 + n * 256 + k] = (f16)W[k * 256 + n];
}

// ---------------- K1: projections (fp32 A, f16 MFMA, f16 out). 64 rows/block.
// (256,2): r18 win -- caps VGPR at 128 (fits) vs ~168 single-arg.
__global__ __launch_bounds__(256, 2) void k1_proj(
    const float* __restrict__ Aq, const float* __restrict__ Ak, const float* __restrict__ Av,
    const f16* __restrict__ WT, f16* __restrict__ Qh, f16* __restrict__ Kh,
    f16* __restrict__ Vh) {
  const int m = blockIdx.y;
  const float* A = (m == 0) ? Aq : (m == 1) ? Ak : Av;
  f16* O = (m == 0) ? Qh : (m == 1) ? Kh : Vh;
  const f16* Wm = WT + m * 65536;
  const int row0 = blockIdx.x * 64;
  const int tid = threadIdx.x;
  const int lane = tid & 63, w = tid >> 6;

  __shared__ f16 Ald[64 * 64];    // [r][k], swizzled ((r&7)<<4) on byte offset
  __shared__ f16 Wld[256 * 64];   // [n][k], swizzled ((n&7)<<4)

  f32x4 acc[16];
#pragma unroll
  for (int i = 0; i < 16; ++i) acc[i] = f32x4{0.f, 0.f, 0.f, 0.f};

  for (int kb = 0; kb < 4; ++kb) {
    __syncthreads();
    {  // stage A tile 64x64 fp32 -> f16
      const int r = tid >> 2, c0 = (tid & 3) * 16;
      const float* src = A + (size_t)(row0 + r) * ND + kb * 64 + c0;
      f16x8 h0, h1;
#pragma unroll
      for (int j = 0; j < 8; ++j) h0[j] = (f16)src[j];
#pragma unroll
      for (int j = 0; j < 8; ++j) h1[j] = (f16)src[8 + j];
      const int sw = (r & 7) << 4;
      *(f16x8*)((char*)Ald + r * 128 + ((c0 * 2) ^ sw)) = h0;
      *(f16x8*)((char*)Ald + r * 128 + ((c0 * 2 + 16) ^ sw)) = h1;
    }
    {  // stage WT tile [256][64] f16
      const int n = tid;
      const f16* src = Wm + n * 256 + kb * 64;
      const int sw = (n & 7) << 4;
#pragma unroll
      for (int j = 0; j < 8; ++j) {
        f16x8 v = *(const f16x8*)(src + j * 8);
        *(f16x8*)((char*)Wld + n * 128 + ((j * 16) ^ sw)) = v;
      }
    }
    __syncthreads();
#pragma unroll
    for (int kk = 0; kk < 2; ++kk) {
      const int arow = w * 16 + (lane & 15);
      const int ko = kk * 64 + (lane >> 4) * 16;
      f16x8 a = *(const f16x8*)((char*)Ald + arow * 128 + (ko ^ ((arow & 7) << 4)));
#pragma unroll
      for (int nt = 0; nt < 16; ++nt) {
        const int n = nt * 16 + (lane & 15);
        f16x8 b = *(const f16x8*)((char*)Wld + n * 128 + (ko ^ ((n & 7) << 4)));
        acc[nt] = mfma16(a, b, acc[nt]);
      }
    }
  }
  const int rl = (lane >> 4) * 4;
#pragma unroll
  for (int nt = 0; nt < 16; ++nt) {
    const int col = nt * 16 + (lane & 15);
#pragma unroll
    for (int j = 0; j < 4; ++j)
      O[(size_t)(row0 + w * 16 + rl + j) * ND + col] = (f16)acc[nt][j];
  }
}

// ---------------- K2: Srel[b] = skew(Q[b] @ (K[b]-Q[b])^T), 128x128 tile.
// E = K - Q computed during B-tile staging. Epilogue writes each QE element
// DIRECTLY to its skew target (bijection); only Srel[q][q+1] stays unwritten
// (the zero column; masked in k3). (256,2): r18 win.
__global__ __launch_bounds__(256, 2) void k2_qe(const f16* __restrict__ Qh,
                                                const f16* __restrict__ Kh,
                                                f16* __restrict__ QEh) {
  const int b = blockIdx.z;
  const int m0 = blockIdx.x * 128, n0 = blockIdx.y * 128;
  const int tid = threadIdx.x, lane = tid & 63, w = tid >> 6;
  const int wr = (w >> 1) * 64, wc = (w & 1) * 64;
  const f16* Qb = Qh + (size_t)b * NL * ND;
  const f16* Kb = Kh + (size_t)b * NL * ND;

  __shared__ f16 As[128 * 64];  // [r][k] swizzled ((r&7)<<4)
  __shared__ f16 Bs[128 * 64];

  f32x4 acc[4][4];
#pragma unroll
  for (int i = 0; i < 4; ++i)
#pragma unroll
    for (int j = 0; j < 4; ++j) acc[i][j] = f32x4{0.f, 0.f, 0.f, 0.f};

  for (int kb = 0; kb < 4; ++kb) {
    __syncthreads();
#pragma unroll
    for (int j = 0; j < 4; ++j) {
      const int c = j * 256 + tid;       // 1024 chunks of 16B
      const int r = c >> 3;
      const int ko = (c & 7) * 16;       // byte offset in row
      const int sw = (r & 7) << 4;
      f16x8 va = *(const f16x8*)((const char*)(Qb + (size_t)(m0 + r) * ND + kb * 64) + ko);
      *(f16x8*)((char*)As + r * 128 + (ko ^ sw)) = va;
      f16x8 vk = *(const f16x8*)((const char*)(Kb + (size_t)(n0 + r) * ND + kb * 64) + ko);
      f16x8 vq = *(const f16x8*)((const char*)(Qb + (size_t)(n0 + r) * ND + kb * 64) + ko);
      *(f16x8*)((char*)Bs + r * 128 + (ko ^ sw)) = vk - vq;  // E = K - Q
    }
    __syncthreads();
#pragma unroll
    for (int kk = 0; kk < 2; ++kk) {
      const int ko = kk * 64 + (lane >> 4) * 16;
      f16x8 a[4], bf[4];
#pragma unroll
      for (int mt = 0; mt < 4; ++mt) {
        const int r = wr + mt * 16 + (lane & 15);
        a[mt] = *(const f16x8*)((char*)As + r * 128 + (ko ^ ((r & 7) << 4)));
      }
#pragma unroll
      for (int nt = 0; nt < 4; ++nt) {
        const int r = wc + nt * 16 + (lane & 15);
        bf[nt] = *(const f16x8*)((char*)Bs + r * 128 + (ko ^ ((r & 7) << 4)));
      }
#pragma unroll
      for (int mt = 0; mt < 4; ++mt)
#pragma unroll
        for (int nt = 0; nt < 4; ++nt) acc[mt][nt] = mfma16(a[mt], bf[nt], acc[mt][nt]);
    }
  }
  f16* outb = QEh + (size_t)b * NL * NL;
#pragma unroll
  for (int mt = 0; mt < 4; ++mt)
#pragma unroll
    for (int nt = 0; nt < 4; ++nt) {
      const int col = n0 + wc + nt * 16 + (lane & 15);
#pragma unroll
      for (int j = 0; j < 4; ++j) {
        const int row = m0 + wr + mt * 16 + (lane >> 4) * 4 + j;
        int qrow, kk2;
        if (col >= (NL - 1) - row) { qrow = row; kk2 = col + row - (NL - 1); }
        else { qrow = row - 1; kk2 = col + row + 1; }
        if (qrow >= 0)
          outb[(size_t)qrow * NL + kk2] = (f16)acc[mt][nt][j];
      }
    }
}

// ---------------- K3p: 4-way key-split flash attention partials (r18 optimum).
// (256,2) = measured VGPR/wave sweet spot (128 VGPR, no spill). Single
// 36.9 KB static LDS buffer. Skewed-Srel row-contiguous gather (r17 win).
// Occupancy knobs closed: single-arg -> 168 VGPR (r9 regress); (256,4) /
// waves_per_eu(4,8) -> 64 VGPR spill (r7/r19); dbuf -> null (r16).
#define KVBUF 36864   // 16384 (K [32][256] swz) + 20480 (V [256][40])
#define NITP 16
__global__ __launch_bounds__(256, 2) void k3_part(
    const f16* __restrict__ Qh, const f16* __restrict__ Kh, const f16* __restrict__ Vh,
    const f16* __restrict__ QEh, f16* __restrict__ Pac, float* __restrict__ Pml) {
  __shared__ char smem[KVBUF];
  const int b = blockIdx.y;
  const int g = blockIdx.z;
  const int q0 = blockIdx.x * 64;
  const int tid = threadIdx.x, lane = tid & 63, w = tid >> 6;
  const int qw = q0 + w * 16;
  const int gi = lane >> 4;

  const f16* Qb = Qh + (size_t)b * NL * ND;
  const f16* Kb = Kh + (size_t)b * NL * ND;
  const f16* Vb = Vh + (size_t)b * NL * ND;
  const f16* QEb = QEh + (size_t)b * NL * NL;  // skewed Srel layout

  f16x8 qf[8];
  {
    const int r = qw + (lane & 15);
#pragma unroll
    for (int kk = 0; kk < 8; ++kk)
      qf[kk] = *(const f16x8*)(Qb + (size_t)r * ND + kk * 32 + gi * 8);
  }

  f32x4 acc[16];
#pragma unroll
  for (int i = 0; i < 16; ++i) acc[i] = f32x4{0.f, 0.f, 0.f, 0.f};
  float mrun = -1e30f, lrun = 0.f;

  f16x8 kst[4], vst[4];
  const int kp = tid & 15, dch = tid >> 4;

  auto stage_load = [&](int t) {
    const f16* Ks = Kb + (size_t)(g * NITP + t) * 32 * ND;
#pragma unroll
    for (int j = 0; j < 4; ++j) {
      const int c = j * 256 + tid;
      kst[j] = *(const f16x8*)(Ks + (c >> 5) * ND + (c & 31) * 8);
    }
    const f16* Vs = Vb + (size_t)(g * NITP + t) * 32 * ND;
    vst[0] = *(const f16x8*)(Vs + (2 * kp) * ND + dch * 16);
    vst[1] = *(const f16x8*)(Vs + (2 * kp) * ND + dch * 16 + 8);
    vst[2] = *(const f16x8*)(Vs + (2 * kp + 1) * ND + dch * 16);
    vst[3] = *(const f16x8*)(Vs + (2 * kp + 1) * ND + dch * 16 + 8);
  };
  auto stage_write = [&]() {
    char* Kld = smem;
    char* Vld = smem + 16384;
#pragma unroll
    for (int j = 0; j < 4; ++j) {
      const int c = j * 256 + tid;
      const int key = c >> 5, d0 = (c & 31) * 16;
      *(f16x8*)(Kld + key * 512 + (d0 ^ ((key & 7) << 4))) = kst[j];
    }
#pragma unroll
    for (int jj = 0; jj < 16; ++jj) {
      f16x2 pr;
      pr.x = (jj < 8) ? vst[0][jj & 7] : vst[1][jj & 7];  // key 2*kp
      pr.y = (jj < 8) ? vst[2][jj & 7] : vst[3][jj & 7];  // key 2*kp+1
      *(f16x2*)(Vld + (dch * 16 + jj) * 80 + kp * 4) = pr;
    }
  };

  stage_load(0);
  stage_write();
  __syncthreads();

  const int qa = qw + (lane & 15);

  for (int t = 0; t < NITP; ++t) {
    const int k0 = (g * NITP + t) * 32;

    // srel gather: ROW-CONTIGUOUS from skewed Srel (2 vector loads/lane)
    float srel[2][4];
#pragma unroll
    for (int nt = 0; nt < 2; ++nt) {
      const int kb2 = k0 + nt * 16 + gi * 4;
      f16x4 v4 = *(const f16x4*)(QEb + (size_t)qa * NL + kb2);
#pragma unroll
      for (int j = 0; j < 4; ++j)
        srel[nt][j] = (kb2 + j == qa + 1) ? 0.f : (float)v4[j];
    }

    if (t < NITP - 1) stage_load(t + 1);

    const char* Kld = smem;
    const char* Vld = smem + 16384;

    f32x4 s[2] = {f32x4{0.f, 0.f, 0.f, 0.f}, f32x4{0.f, 0.f, 0.f, 0.f}};
#pragma unroll
    for (int kk = 0; kk < 8; ++kk) {
      const int ko = kk * 64 + gi * 16;
#pragma unroll
      for (int nt = 0; nt < 2; ++nt) {
        const int key = nt * 16 + (lane & 15);
        f16x8 af = *(const f16x8*)(Kld + key * 512 + (ko ^ ((key & 7) << 4)));
        s[nt] = mfma16(af, qf[kk], s[nt]);
      }
    }

    float sv[2][4];
#pragma unroll
    for (int nt = 0; nt < 2; ++nt)
#pragma unroll
      for (int j = 0; j < 4; ++j) sv[nt][j] = 0.0625f * (s[nt][j] + srel[nt][j]);

    float pm = fmaxf(fmaxf(fmaxf(sv[0][0], sv[0][1]), fmaxf(sv[0][2], sv[0][3])),
                     fmaxf(fmaxf(sv[1][0], sv[1][1]), fmaxf(sv[1][2], sv[1][3])));
    pm = fmaxf(pm, __shfl_xor(pm, 16, 64));
    pm = fmaxf(pm, __shfl_xor(pm, 32, 64));

    float p[2][4];
    if (__any(pm > mrun + 8.f)) {
      const float mn = fmaxf(mrun, pm);
      const float al = __expf(mrun - mn);
      mrun = mn;
#pragma unroll
      for (int nt = 0; nt < 2; ++nt)
#pragma unroll
        for (int j = 0; j < 4; ++j) p[nt][j] = __expf(sv[nt][j] - mrun);
      float rs = (p[0][0] + p[0][1]) + (p[0][2] + p[0][3]) +
                 (p[1][0] + p[1][1]) + (p[1][2] + p[1][3]);
      rs += __shfl_xor(rs, 16, 64);
      rs += __shfl_xor(rs, 32, 64);
      lrun = lrun * al + rs;
#pragma unroll
      for (int j = 0; j < 4; ++j) {
        const float aj = __shfl(al, gi * 4 + j, 16);
#pragma unroll
        for (int dt = 0; dt < 16; ++dt) acc[dt][j] *= aj;
      }
    } else {
#pragma unroll
      for (int nt = 0; nt < 2; ++nt)
#pragma unroll
        for (int j = 0; j < 4; ++j) p[nt][j] = __expf(sv[nt][j] - mrun);
      float rs = (p[0][0] + p[0][1]) + (p[0][2] + p[0][3]) +
                 (p[1][0] + p[1][1]) + (p[1][2] + p[1][3]);
      rs += __shfl_xor(rs, 16, 64);
      rs += __shfl_xor(rs, 32, 64);
      lrun += rs;
    }

    union {
      fp16x2 h2[2];
      f16x4 h4;
    } pu0, pu1;
    pu0.h2[0] = __builtin_amdgcn_cvt_pkrtz(p[0][0], p[0][1]);
    pu0.h2[1] = __builtin_amdgcn_cvt_pkrtz(p[0][2], p[0][3]);
    pu1.h2[0] = __builtin_amdgcn_cvt_pkrtz(p[1][0], p[1][1]);
    pu1.h2[1] = __builtin_amdgcn_cvt_pkrtz(p[1][2], p[1][3]);

#pragma unroll
    for (int dt = 0; dt < 16; ++dt) {
      const char* vrow = Vld + (dt * 16 + (lane & 15)) * 80 + 8 * gi;
      f16x4 v0 = *(const f16x4*)(vrow);
      f16x4 v1 = *(const f16x4*)(vrow + 32);
      acc[dt] = __builtin_amdgcn_mfma_f32_16x16x16f16(pu0.h4, v0, acc[dt], 0, 0, 0);
      acc[dt] = __builtin_amdgcn_mfma_f32_16x16x16f16(pu1.h4, v1, acc[dt], 0, 0, 0);
    }

    __syncthreads();
    if (t < NITP - 1) stage_write();
    __syncthreads();
  }

  // ---- write l-normalized partials (f16) ----
  const float inv = 1.f / lrun;
  f16* Pb = Pac + ((size_t)g * (NB * NL) + (size_t)b * NL) * ND;
#pragma unroll
  for (int j = 0; j < 4; ++j) {
    const float invj = __shfl(inv, gi * 4 + j, 16);
    const int row = qw + gi * 4 + j;
#pragma unroll
    for (int dt = 0; dt < 16; ++dt)
      Pb[(size_t)row * ND + dt * 16 + (lane & 15)] = (f16)(acc[dt][j] * invj);
  }
  if (lane < 16) {
    const size_t r = (size_t)g * (NB * NL) + (size_t)b * NL + qw + lane;
    Pml[r * 2 + 0] = mrun;
    Pml[r * 2 + 1] = lrun;
  }
}

// ---------------- K4: combine 4 key-group normalized partials -> output
__global__ __launch_bounds__(256) void k4_comb(const f16* __restrict__ Pac,
                                               const float* __restrict__ Pml,
                                               float* __restrict__ Out) {
  const int row = blockIdx.x * 4 + (threadIdx.x >> 6);
  const int lane = threadIdx.x & 63;
  float m[4], l[4];
#pragma unroll
  for (int gq = 0; gq < 4; ++gq) {
    const size_t r = (size_t)gq * (NB * NL) + row;
    m[gq] = Pml[r * 2 + 0];
    l[gq] = Pml[r * 2 + 1];
  }
  const float M = fmaxf(fmaxf(m[0], m[1]), fmaxf(m[2], m[3]));
  float wgt[4];
  float denom = 0.f;
#pragma unroll
  for (int gq = 0; gq < 4; ++gq) {
    wgt[gq] = l[gq] * __expf(m[gq] - M);
    denom += wgt[gq];
  }
  const float inv = 1.f / denom;
  const size_t base = (size_t)row * ND + lane * 4;
  float o[4] = {0.f, 0.f, 0.f, 0.f};
#pragma unroll
  for (int gq = 0; gq < 4; ++gq) {
    f16x4 p = *(const f16x4*)(Pac + (size_t)gq * (NB * NL) * ND + base);
    const float s = wgt[gq] * inv;
#pragma unroll
    for (int e = 0; e < 4; ++e) o[e] += (float)p[e] * s;
  }
  f32x4 ov = {o[0], o[1], o[2], o[3]};
  *(f32x4*)(Out + base) = ov;
}

// ---------------- K3 fallback (r6 form, skewed-Srel gather), for small ws.
#define NIT 32
__global__ __launch_bounds__(512, 2) void k3_attn(
    const f16* __restrict__ Qh, const f16* __restrict__ Kh, const f16* __restrict__ Vh,
    const f16* __restrict__ QEh, float* __restrict__ Out) {
  extern __shared__ char smemd[];  // 73728 B
  const int b = blockIdx.y;
  const int q0 = blockIdx.x * 64;
  const int tid = threadIdx.x, lane = tid & 63, w = tid >> 6;
  const int g = w >> 2, wq = w & 3;
  const int qw = q0 + wq * 16;
  const int lt = tid & 255;
  const int gi = lane >> 4;

  float* Cst = (float*)smemd;
  float* ml = (float*)(smemd + 65536);

  const f16* Qb = Qh + (size_t)b * NL * ND;
  const f16* Kb = Kh + (size_t)b * NL * ND;
  const f16* Vb = Vh + (size_t)b * NL * ND;
  const f16* QEb = QEh + (size_t)b * NL * NL;  // skewed Srel layout

  f16x8 qf[8];
  {
    const int r = qw + (lane & 15);
#pragma unroll
    for (int kk = 0; kk < 8; ++kk)
      qf[kk] = *(const f16x8*)(Qb + (size_t)r * ND + kk * 32 + gi * 8);
  }

  f32x4 acc[16];
#pragma unroll
  for (int i = 0; i < 16; ++i) acc[i] = f32x4{0.f, 0.f, 0.f, 0.f};
  float mrun = -1e30f, lrun = 0.f;

  f16x8 kst[4], vst[4];
  const int kp = lt & 15, dch = lt >> 4;

  auto stage_load = [&](int t) {
    const f16* Ks = Kb + (size_t)(g * NIT + t) * 32 * ND;
#pragma unroll
    for (int j = 0; j < 4; ++j) {
      const int c = j * 256 + lt;
      kst[j] = *(const f16x8*)(Ks + (c >> 5) * ND + (c & 31) * 8);
    }
    const f16* Vs = Vb + (size_t)(g * NIT + t) * 32 * ND;
    vst[0] = *(const f16x8*)(Vs + (2 * kp) * ND + dch * 16);
    vst[1] = *(const f16x8*)(Vs + (2 * kp) * ND + dch * 16 + 8);
    vst[2] = *(const f16x8*)(Vs + (2 * kp + 1) * ND + dch * 16);
    vst[3] = *(const f16x8*)(Vs + (2 * kp + 1) * ND + dch * 16 + 8);
  };
  auto stage_write = [&]() {
    char* Kld = smemd + g * KVBUF;
    char* Vld = Kld + 16384;
#pragma unroll
    for (int j = 0; j < 4; ++j) {
      const int c = j * 256 + lt;
      const int key = c >> 5, d0 = (c & 31) * 16;
      *(f16x8*)(Kld + key * 512 + (d0 ^ ((key & 7) << 4))) = kst[j];
    }
#pragma unroll
    for (int jj = 0; jj < 16; ++jj) {
      f16x2 pr;
      pr.x = (jj < 8) ? vst[0][jj & 7] : vst[1][jj & 7];
      pr.y = (jj < 8) ? vst[2][jj & 7] : vst[3][jj & 7];
      *(f16x2*)(Vld + (dch * 16 + jj) * 80 + kp * 4) = pr;
    }
  };

  stage_load(0);
  stage_write();
  __syncthreads();

  const int qa = qw + (lane & 15);

  for (int t = 0; t < NIT; ++t) {
    const int k0 = (g * NIT + t) * 32;

    float srel[2][4];
#pragma unroll
    for (int nt = 0; nt < 2; ++nt) {
      const int kb2 = k0 + nt * 16 + gi * 4;
      f16x4 v4 = *(const f16x4*)(QEb + (size_t)qa * NL + kb2);
#pragma unroll
      for (int j = 0; j < 4; ++j)
        srel[nt][j] = (kb2 + j == qa + 1) ? 0.f : (float)v4[j];
    }

    if (t < NIT - 1) stage_load(t + 1);

    const char* Kld = smemd + g * KVBUF;
    const char* Vld = Kld + 16384;

    f32x4 s[2] = {f32x4{0.f, 0.f, 0.f, 0.f}, f32x4{0.f, 0.f, 0.f, 0.f}};
#pragma unroll
    for (int kk = 0; kk < 8; ++kk) {
      const int ko = kk * 64 + gi * 16;
#pragma unroll
      for (int nt = 0; nt < 2; ++nt) {
        const int key = nt * 16 + (lane & 15);
        f16x8 af = *(const f16x8*)(Kld + key * 512 + (ko ^ ((key & 7) << 4)));
        s[nt] = mfma16(af, qf[kk], s[nt]);
      }
    }

    float sv[2][4];
#pragma unroll
    for (int nt = 0; nt < 2; ++nt)
#pragma unroll
      for (int j = 0; j < 4; ++j) sv[nt][j] = 0.0625f * (s[nt][j] + srel[nt][j]);

    float pm = fmaxf(fmaxf(fmaxf(sv[0][0], sv[0][1]), fmaxf(sv[0][2], sv[0][3])),
                     fmaxf(fmaxf(sv[1][0], sv[1][1]), fmaxf(sv[1][2], sv[1][3])));
    pm = fmaxf(pm, __shfl_xor(pm, 16, 64));
    pm = fmaxf(pm, __shfl_xor(pm, 32, 64));

    float p[2][4];
    if (__any(pm > mrun + 8.f)) {
      const float mn = fmaxf(mrun, pm);
      const float al = __expf(mrun - mn);
      mrun = mn;
#pragma unroll
      for (int nt = 0; nt < 2; ++nt)
#pragma unroll
        for (int j = 0; j < 4; ++j) p[nt][j] = __expf(sv[nt][j] - mrun);
      float rs = (p[0][0] + p[0][1]) + (p[0][2] + p[0][3]) +
                 (p[1][0] + p[1][1]) + (p[1][2] + p[1][3]);
      rs += __shfl_xor(rs, 16, 64);
      rs += __shfl_xor(rs, 32, 64);
      lrun = lrun * al + rs;
#pragma unroll
      for (int j = 0; j < 4; ++j) {
        const float aj = __shfl(al, gi * 4 + j, 16);
#pragma unroll
        for (int dt = 0; dt < 16; ++dt) acc[dt][j] *= aj;
      }
    } else {
#pragma unroll
      for (int nt = 0; nt < 2; ++nt)
#pragma unroll
        for (int j = 0; j < 4; ++j) p[nt][j] = __expf(sv[nt][j] - mrun);
      float rs = (p[0][0] + p[0][1]) + (p[0][2] + p[0][3]) +
                 (p[1][0] + p[1][1]) + (p[1][2] + p[1][3]);
      rs += __shfl_xor(rs, 16, 64);
      rs += __shfl_xor(rs, 32, 64);
      lrun += rs;
    }

    union {
      fp16x2 h2[2];
      f16x4 h4;
    } pu0, pu1;
    pu0.h2[0] = __builtin_amdgcn_cvt_pkrtz(p[0][0], p[0][1]);
    pu0.h2[1] = __builtin_amdgcn_cvt_pkrtz(p[0][2], p[0][3]);
    pu1.h2[0] = __builtin_amdgcn_cvt_pkrtz(p[1][0], p[1][1]);
    pu1.h2[1] = __builtin_amdgcn_cvt_pkrtz(p[1][2], p[1][3]);

#pragma unroll
    for (int dt = 0; dt < 16; ++dt) {
      const char* vrow = Vld + (dt * 16 + (lane & 15)) * 80 + 8 * gi;
      f16x4 v0 = *(const f16x4*)(vrow);
      f16x4 v1 = *(const f16x4*)(vrow + 32);
      acc[dt] = __builtin_amdgcn_mfma_f32_16x16x16f16(pu0.h4, v0, acc[dt], 0, 0, 0);
      acc[dt] = __builtin_amdgcn_mfma_f32_16x16x16f16(pu1.h4, v1, acc[dt], 0, 0, 0);
    }

    __syncthreads();
    if (t < NIT - 1) stage_write();
    __syncthreads();
  }

  if (g == 1) {
#pragma unroll
    for (int dt = 0; dt < 16; ++dt)
#pragma unroll
      for (int j = 0; j < 4; ++j)
        Cst[wq * 4096 + (gi * 4 + j) * 256 + dt * 16 + (lane & 15)] = acc[dt][j];
    if (lane < 16) {
      ml[(wq * 16 + lane) * 2 + 0] = mrun;
      ml[(wq * 16 + lane) * 2 + 1] = lrun;
    }
  }
  __syncthreads();
  if (g == 0) {
    float* Ob = Out + (size_t)b * NL * ND;
#pragma unroll
    for (int j = 0; j < 4; ++j) {
      const int rloc = gi * 4 + j;
      const float m0r = __shfl(mrun, rloc, 16);
      const float l0r = __shfl(lrun, rloc, 16);
      const float m1 = ml[(wq * 16 + rloc) * 2 + 0];
      const float l1 = ml[(wq * 16 + rloc) * 2 + 1];
      const float M = fmaxf(m0r, m1);
      const float c0 = __expf(m0r - M), c1 = __expf(m1 - M);
      const float inv = 1.f / (l0r * c0 + l1 * c1);
      const int row = qw + rloc;
#pragma unroll
      for (int dt = 0; dt < 16; ++dt) {
        const float o1 = Cst[wq * 4096 + rloc * 256 + dt * 16 + (lane & 15)];
        Ob[(size_t)row * ND + dt * 16 + (lane & 15)] = (acc[dt][j] * c0 + o1 * c1) * inv;
      }
    }
  }
}

extern "C" void kernel_launch(void* const* d_in, const int* in_sizes, int n_in,
                              void* d_out, int out_size, void* d_ws, size_t ws_size,
                              hipStream_t stream) {
  (void)in_sizes; (void)n_in; (void)out_size;
  const float* inQ = (const float*)d_in[0];
  const float* inK = (const float*)d_in[1];
  const float* inV = (const float*)d_in[2];
  const float* Wq = (const float*)d_in[3];
  const float* Wk = (const float*)d_in[4];
  const float* Wv = (const float*)d_in[5];
  float* out = (float*)d_out;

  // ws layout (f16): Qh,Kh,Vh [B*L*D]; WT [3*256*256]; QEh [B*L*L] (SKEWED);
  // Pac f16 [4][B*L][D]; then (f32) Pml [4][B*L][2].
  f16* ws = (f16*)d_ws;
  f16* Qh = ws;
  f16* Kh = Qh + (size_t)QKV_ELEMS;
  f16* Vh = Kh + (size_t)QKV_ELEMS;
  f16* WT = Vh + (size_t)QKV_ELEMS;
  f16* QEh = WT + 3 * 65536;
  f16* Pac = QEh + (size_t)NB * NL * NL;
  float* Pml = (float*)(Pac + (size_t)4 * QKV_ELEMS);
  const size_t need = (size_t)((char*)(Pml + 4 * NB * NL * 2) - (char*)d_ws);

  k0_wt<<<dim3(768), dim3(256), 0, stream>>>(Wq, Wk, Wv, WT);
  k1_proj<<<dim3(256, 3), dim3(256), 0, stream>>>(inQ, inK, inV, WT, Qh, Kh, Vh);
  k2_qe<<<dim3(16, 16, 8), dim3(256), 0, stream>>>(Qh, Kh, QEh);
  if (ws_size >= need) {
    k3_part<<<dim3(32, 8, 4), dim3(256), 0, stream>>>(Qh, Kh, Vh, QEh, Pac, Pml);
    k4_comb<<<dim3(NB * NL / 4), dim3(256), 0, stream>>>(Pac, Pml, out);
  } else {
    k3_attn<<<dim3(32, 8), dim3(512), 73728, stream>>>(Qh, Kh, Vh, QEh, out);
  }
}

// Round 21
// 156.515 us; speedup vs baseline: 3.8216x; 1.0517x over previous
//
#include <hip/hip_runtime.h>
#include <hip/hip_fp16.h>
#include <stdint.h>

typedef _Float16 f16;
typedef _Float16 f16x2 __attribute__((ext_vector_type(2)));
typedef _Float16 f16x4 __attribute__((ext_vector_type(4)));
typedef _Float16 f16x8 __attribute__((ext_vector_type(8)));
typedef __fp16 fp16x2 __attribute__((ext_vector_type(2)));  // cvt_pkrtz return type
typedef float f32x4 __attribute__((ext_vector_type(4)));

#define NB 8
#define NL 2048
#define ND 256
#define QKV_ELEMS (NB * NL * ND)   // 4194304

__device__ __forceinline__ f32x4 mfma16(f16x8 a, f16x8 b, f32x4 c) {
  return __builtin_amdgcn_mfma_f32_16x16x32_f16(a, b, c, 0, 0, 0);
}

// ---------------- K0: transpose+convert weights: WT[m][n][k] = (f16)W_m[k][n]
__global__ void k0_wt(const float* __restrict__ Wq, const float* __restrict__ Wk,
                      const float* __restrict__ Wv, f16* __restrict__ WT) {
  int id = blockIdx.x * 256 + threadIdx.x;  // 0..196607
  int m = id >> 16;
  int r = id & 65535;
  int k = r >> 8, n = r & 255;
  const float* W = (m == 0) ? Wq : (m == 1) ? Wk : Wv;
  WT[m * 65536 + n * 256 + k] = (f16)W[k * 256 + n];
}

// ---------------- K1: projections (fp32 A, f16 MFMA, f16 out). 64 rows/block.
// (256,2): r18 win -- caps VGPR at 128 (fits) vs ~168 single-arg.
__global__ __launch_bounds__(256, 2) void k1_proj(
    const float* __restrict__ Aq, const float* __restrict__ Ak, const float* __restrict__ Av,
    const f16* __restrict__ WT, f16* __restrict__ Qh, f16* __restrict__ Kh,
    f16* __restrict__ Vh) {
  const int m = blockIdx.y;
  const float* A = (m == 0) ? Aq : (m == 1) ? Ak : Av;
  f16* O = (m == 0) ? Qh : (m == 1) ? Kh : Vh;
  const f16* Wm = WT + m * 65536;
  const int row0 = blockIdx.x * 64;
  const int tid = threadIdx.x;
  const int lane = tid & 63, w = tid >> 6;

  __shared__ f16 Ald[64 * 64];    // [r][k], swizzled ((r&7)<<4) on byte offset
  __shared__ f16 Wld[256 * 64];   // [n][k], swizzled ((n&7)<<4)

  f32x4 acc[16];
#pragma unroll
  for (int i = 0; i < 16; ++i) acc[i] = f32x4{0.f, 0.f, 0.f, 0.f};

  for (int kb = 0; kb < 4; ++kb) {
    __syncthreads();
    {  // stage A tile 64x64 fp32 -> f16
      const int r = tid >> 2, c0 = (tid & 3) * 16;
      const float* src = A + (size_t)(row0 + r) * ND + kb * 64 + c0;
      f16x8 h0, h1;
#pragma unroll
      for (int j = 0; j < 8; ++j) h0[j] = (f16)src[j];
#pragma unroll
      for (int j = 0; j < 8; ++j) h1[j] = (f16)src[8 + j];
      const int sw = (r & 7) << 4;
      *(f16x8*)((char*)Ald + r * 128 + ((c0 * 2) ^ sw)) = h0;
      *(f16x8*)((char*)Ald + r * 128 + ((c0 * 2 + 16) ^ sw)) = h1;
    }
    {  // stage WT tile [256][64] f16
      const int n = tid;
      const f16* src = Wm + n * 256 + kb * 64;
      const int sw = (n & 7) << 4;
#pragma unroll
      for (int j = 0; j < 8; ++j) {
        f16x8 v = *(const f16x8*)(src + j * 8);
        *(f16x8*)((char*)Wld + n * 128 + ((j * 16) ^ sw)) = v;
      }
    }
    __syncthreads();
#pragma unroll
    for (int kk = 0; kk < 2; ++kk) {
      const int arow = w * 16 + (lane & 15);
      const int ko = kk * 64 + (lane >> 4) * 16;
      f16x8 a = *(const f16x8*)((char*)Ald + arow * 128 + (ko ^ ((arow & 7) << 4)));
#pragma unroll
      for (int nt = 0; nt < 16; ++nt) {
        const int n = nt * 16 + (lane & 15);
        f16x8 b = *(const f16x8*)((char*)Wld + n * 128 + (ko ^ ((n & 7) << 4)));
        acc[nt] = mfma16(a, b, acc[nt]);
      }
    }
  }
  const int rl = (lane >> 4) * 4;
#pragma unroll
  for (int nt = 0; nt < 16; ++nt) {
    const int col = nt * 16 + (lane & 15);
#pragma unroll
    for (int j = 0; j < 4; ++j)
      O[(size_t)(row0 + w * 16 + rl + j) * ND + col] = (f16)acc[nt][j];
  }
}

// ---------------- K2: Srel[b] = skew(Q[b] @ (K[b]-Q[b])^T), 128x128 tile.
// E = K - Q computed during B-tile staging. Epilogue writes each QE element
// DIRECTLY to its skew target (bijection); only Srel[q][q+1] stays unwritten
// (the zero column; masked in k3). (256,2): r18 win.
__global__ __launch_bounds__(256, 2) void k2_qe(const f16* __restrict__ Qh,
                                                const f16* __restrict__ Kh,
                                                f16* __restrict__ QEh) {
  const int b = blockIdx.z;
  const int m0 = blockIdx.x * 128, n0 = blockIdx.y * 128;
  const int tid = threadIdx.x, lane = tid & 63, w = tid >> 6;
  const int wr = (w >> 1) * 64, wc = (w & 1) * 64;
  const f16* Qb = Qh + (size_t)b * NL * ND;
  const f16* Kb = Kh + (size_t)b * NL * ND;

  __shared__ f16 As[128 * 64];  // [r][k] swizzled ((r&7)<<4)
  __shared__ f16 Bs[128 * 64];

  f32x4 acc[4][4];
#pragma unroll
  for (int i = 0; i < 4; ++i)
#pragma unroll
    for (int j = 0; j < 4; ++j) acc[i][j] = f32x4{0.f, 0.f, 0.f, 0.f};

  for (int kb = 0; kb < 4; ++kb) {
    __syncthreads();
#pragma unroll
    for (int j = 0; j < 4; ++j) {
      const int c = j * 256 + tid;       // 1024 chunks of 16B
      const int r = c >> 3;
      const int ko = (c & 7) * 16;       // byte offset in row
      const int sw = (r & 7) << 4;
      f16x8 va = *(const f16x8*)((const char*)(Qb + (size_t)(m0 + r) * ND + kb * 64) + ko);
      *(f16x8*)((char*)As + r * 128 + (ko ^ sw)) = va;
      f16x8 vk = *(const f16x8*)((const char*)(Kb + (size_t)(n0 + r) * ND + kb * 64) + ko);
      f16x8 vq = *(const f16x8*)((const char*)(Qb + (size_t)(n0 + r) * ND + kb * 64) + ko);
      *(f16x8*)((char*)Bs + r * 128 + (ko ^ sw)) = vk - vq;  // E = K - Q
    }
    __syncthreads();
#pragma unroll
    for (int kk = 0; kk < 2; ++kk) {
      const int ko = kk * 64 + (lane >> 4) * 16;
      f16x8 a[4], bf[4];
#pragma unroll
      for (int mt = 0; mt < 4; ++mt) {
        const int r = wr + mt * 16 + (lane & 15);
        a[mt] = *(const f16x8*)((char*)As + r * 128 + (ko ^ ((r & 7) << 4)));
      }
#pragma unroll
      for (int nt = 0; nt < 4; ++nt) {
        const int r = wc + nt * 16 + (lane & 15);
        bf[nt] = *(const f16x8*)((char*)Bs + r * 128 + (ko ^ ((r & 7) << 4)));
      }
#pragma unroll
      for (int mt = 0; mt < 4; ++mt)
#pragma unroll
        for (int nt = 0; nt < 4; ++nt) acc[mt][nt] = mfma16(a[mt], bf[nt], acc[mt][nt]);
    }
  }
  f16* outb = QEh + (size_t)b * NL * NL;
#pragma unroll
  for (int mt = 0; mt < 4; ++mt)
#pragma unroll
    for (int nt = 0; nt < 4; ++nt) {
      const int col = n0 + wc + nt * 16 + (lane & 15);
#pragma unroll
      for (int j = 0; j < 4; ++j) {
        const int row = m0 + wr + mt * 16 + (lane >> 4) * 4 + j;
        int qrow, kk2;
        if (col >= (NL - 1) - row) { qrow = row; kk2 = col + row - (NL - 1); }
        else { qrow = row - 1; kk2 = col + row + 1; }
        if (qrow >= 0)
          outb[(size_t)qrow * NL + kk2] = (f16)acc[mt][nt][j];
      }
    }
}

// ---------------- K3p: 2-WAY key-split flash attention partials.
// r18 structure (single 36.9KB LDS buffer, (256,2), skewed-Srel gather) with
// the split reduced 4->2: residency is pinned at 2 blocks/CU anyway (128
// VGPR), so 512 blocks x NITP=32 keeps k3p work/hiding identical while
// halving Pac write traffic and k4's partial reads, and amortizing the
// per-block prologue/epilogue over 2x iterations.
#define KVBUF 36864   // 16384 (K [32][256] swz) + 20480 (V [256][40])
#define NGRP 2
#define NITP 32
__global__ __launch_bounds__(256, 2) void k3_part(
    const f16* __restrict__ Qh, const f16* __restrict__ Kh, const f16* __restrict__ Vh,
    const f16* __restrict__ QEh, f16* __restrict__ Pac, float* __restrict__ Pml) {
  __shared__ char smem[KVBUF];
  const int b = blockIdx.y;
  const int g = blockIdx.z;
  const int q0 = blockIdx.x * 64;
  const int tid = threadIdx.x, lane = tid & 63, w = tid >> 6;
  const int qw = q0 + w * 16;
  const int gi = lane >> 4;

  const f16* Qb = Qh + (size_t)b * NL * ND;
  const f16* Kb = Kh + (size_t)b * NL * ND;
  const f16* Vb = Vh + (size_t)b * NL * ND;
  const f16* QEb = QEh + (size_t)b * NL * NL;  // skewed Srel layout

  f16x8 qf[8];
  {
    const int r = qw + (lane & 15);
#pragma unroll
    for (int kk = 0; kk < 8; ++kk)
      qf[kk] = *(const f16x8*)(Qb + (size_t)r * ND + kk * 32 + gi * 8);
  }

  f32x4 acc[16];
#pragma unroll
  for (int i = 0; i < 16; ++i) acc[i] = f32x4{0.f, 0.f, 0.f, 0.f};
  float mrun = -1e30f, lrun = 0.f;

  f16x8 kst[4], vst[4];
  const int kp = tid & 15, dch = tid >> 4;

  auto stage_load = [&](int t) {
    const f16* Ks = Kb + (size_t)(g * NITP + t) * 32 * ND;
#pragma unroll
    for (int j = 0; j < 4; ++j) {
      const int c = j * 256 + tid;
      kst[j] = *(const f16x8*)(Ks + (c >> 5) * ND + (c & 31) * 8);
    }
    const f16* Vs = Vb + (size_t)(g * NITP + t) * 32 * ND;
    vst[0] = *(const f16x8*)(Vs + (2 * kp) * ND + dch * 16);
    vst[1] = *(const f16x8*)(Vs + (2 * kp) * ND + dch * 16 + 8);
    vst[2] = *(const f16x8*)(Vs + (2 * kp + 1) * ND + dch * 16);
    vst[3] = *(const f16x8*)(Vs + (2 * kp + 1) * ND + dch * 16 + 8);
  };
  auto stage_write = [&]() {
    char* Kld = smem;
    char* Vld = smem + 16384;
#pragma unroll
    for (int j = 0; j < 4; ++j) {
      const int c = j * 256 + tid;
      const int key = c >> 5, d0 = (c & 31) * 16;
      *(f16x8*)(Kld + key * 512 + (d0 ^ ((key & 7) << 4))) = kst[j];
    }
#pragma unroll
    for (int jj = 0; jj < 16; ++jj) {
      f16x2 pr;
      pr.x = (jj < 8) ? vst[0][jj & 7] : vst[1][jj & 7];  // key 2*kp
      pr.y = (jj < 8) ? vst[2][jj & 7] : vst[3][jj & 7];  // key 2*kp+1
      *(f16x2*)(Vld + (dch * 16 + jj) * 80 + kp * 4) = pr;
    }
  };

  stage_load(0);
  stage_write();
  __syncthreads();

  const int qa = qw + (lane & 15);

  for (int t = 0; t < NITP; ++t) {
    const int k0 = (g * NITP + t) * 32;

    // srel gather: ROW-CONTIGUOUS from skewed Srel (2 vector loads/lane)
    float srel[2][4];
#pragma unroll
    for (int nt = 0; nt < 2; ++nt) {
      const int kb2 = k0 + nt * 16 + gi * 4;
      f16x4 v4 = *(const f16x4*)(QEb + (size_t)qa * NL + kb2);
#pragma unroll
      for (int j = 0; j < 4; ++j)
        srel[nt][j] = (kb2 + j == qa + 1) ? 0.f : (float)v4[j];
    }

    if (t < NITP - 1) stage_load(t + 1);

    const char* Kld = smem;
    const char* Vld = smem + 16384;

    f32x4 s[2] = {f32x4{0.f, 0.f, 0.f, 0.f}, f32x4{0.f, 0.f, 0.f, 0.f}};
#pragma unroll
    for (int kk = 0; kk < 8; ++kk) {
      const int ko = kk * 64 + gi * 16;
#pragma unroll
      for (int nt = 0; nt < 2; ++nt) {
        const int key = nt * 16 + (lane & 15);
        f16x8 af = *(const f16x8*)(Kld + key * 512 + (ko ^ ((key & 7) << 4)));
        s[nt] = mfma16(af, qf[kk], s[nt]);
      }
    }

    float sv[2][4];
#pragma unroll
    for (int nt = 0; nt < 2; ++nt)
#pragma unroll
      for (int j = 0; j < 4; ++j) sv[nt][j] = 0.0625f * (s[nt][j] + srel[nt][j]);

    float pm = fmaxf(fmaxf(fmaxf(sv[0][0], sv[0][1]), fmaxf(sv[0][2], sv[0][3])),
                     fmaxf(fmaxf(sv[1][0], sv[1][1]), fmaxf(sv[1][2], sv[1][3])));
    pm = fmaxf(pm, __shfl_xor(pm, 16, 64));
    pm = fmaxf(pm, __shfl_xor(pm, 32, 64));

    float p[2][4];
    if (__any(pm > mrun + 8.f)) {
      const float mn = fmaxf(mrun, pm);
      const float al = __expf(mrun - mn);
      mrun = mn;
#pragma unroll
      for (int nt = 0; nt < 2; ++nt)
#pragma unroll
        for (int j = 0; j < 4; ++j) p[nt][j] = __expf(sv[nt][j] - mrun);
      float rs = (p[0][0] + p[0][1]) + (p[0][2] + p[0][3]) +
                 (p[1][0] + p[1][1]) + (p[1][2] + p[1][3]);
      rs += __shfl_xor(rs, 16, 64);
      rs += __shfl_xor(rs, 32, 64);
      lrun = lrun * al + rs;
#pragma unroll
      for (int j = 0; j < 4; ++j) {
        const float aj = __shfl(al, gi * 4 + j, 16);
#pragma unroll
        for (int dt = 0; dt < 16; ++dt) acc[dt][j] *= aj;
      }
    } else {
#pragma unroll
      for (int nt = 0; nt < 2; ++nt)
#pragma unroll
        for (int j = 0; j < 4; ++j) p[nt][j] = __expf(sv[nt][j] - mrun);
      float rs = (p[0][0] + p[0][1]) + (p[0][2] + p[0][3]) +
                 (p[1][0] + p[1][1]) + (p[1][2] + p[1][3]);
      rs += __shfl_xor(rs, 16, 64);
      rs += __shfl_xor(rs, 32, 64);
      lrun += rs;
    }

    union {
      fp16x2 h2[2];
      f16x4 h4;
    } pu0, pu1;
    pu0.h2[0] = __builtin_amdgcn_cvt_pkrtz(p[0][0], p[0][1]);
    pu0.h2[1] = __builtin_amdgcn_cvt_pkrtz(p[0][2], p[0][3]);
    pu1.h2[0] = __builtin_amdgcn_cvt_pkrtz(p[1][0], p[1][1]);
    pu1.h2[1] = __builtin_amdgcn_cvt_pkrtz(p[1][2], p[1][3]);

#pragma unroll
    for (int dt = 0; dt < 16; ++dt) {
      const char* vrow = Vld + (dt * 16 + (lane & 15)) * 80 + 8 * gi;
      f16x4 v0 = *(const f16x4*)(vrow);
      f16x4 v1 = *(const f16x4*)(vrow + 32);
      acc[dt] = __builtin_amdgcn_mfma_f32_16x16x16f16(pu0.h4, v0, acc[dt], 0, 0, 0);
      acc[dt] = __builtin_amdgcn_mfma_f32_16x16x16f16(pu1.h4, v1, acc[dt], 0, 0, 0);
    }

    __syncthreads();
    if (t < NITP - 1) stage_write();
    __syncthreads();
  }

  // ---- write l-normalized partials (f16) ----
  const float inv = 1.f / lrun;
  f16* Pb = Pac + ((size_t)g * (NB * NL) + (size_t)b * NL) * ND;
#pragma unroll
  for (int j = 0; j < 4; ++j) {
    const float invj = __shfl(inv, gi * 4 + j, 16);
    const int row = qw + gi * 4 + j;
#pragma unroll
    for (int dt = 0; dt < 16; ++dt)
      Pb[(size_t)row * ND + dt * 16 + (lane & 15)] = (f16)(acc[dt][j] * invj);
  }
  if (lane < 16) {
    const size_t r = (size_t)g * (NB * NL) + (size_t)b * NL + qw + lane;
    Pml[r * 2 + 0] = mrun;
    Pml[r * 2 + 1] = lrun;
  }
}

// ---------------- K4: combine NGRP key-group normalized partials -> output
__global__ __launch_bounds__(256) void k4_comb(const f16* __restrict__ Pac,
                                               const float* __restrict__ Pml,
                                               float* __restrict__ Out) {
  const int row = blockIdx.x * 4 + (threadIdx.x >> 6);
  const int lane = threadIdx.x & 63;
  float m[NGRP], l[NGRP];
#pragma unroll
  for (int gq = 0; gq < NGRP; ++gq) {
    const size_t r = (size_t)gq * (NB * NL) + row;
    m[gq] = Pml[r * 2 + 0];
    l[gq] = Pml[r * 2 + 1];
  }
  float M = m[0];
#pragma unroll
  for (int gq = 1; gq < NGRP; ++gq) M = fmaxf(M, m[gq]);
  float wgt[NGRP];
  float denom = 0.f;
#pragma unroll
  for (int gq = 0; gq < NGRP; ++gq) {
    wgt[gq] = l[gq] * __expf(m[gq] - M);
    denom += wgt[gq];
  }
  const float inv = 1.f / denom;
  const size_t base = (size_t)row * ND + lane * 4;
  float o[4] = {0.f, 0.f, 0.f, 0.f};
#pragma unroll
  for (int gq = 0; gq < NGRP; ++gq) {
    f16x4 p = *(const f16x4*)(Pac + (size_t)gq * (NB * NL) * ND + base);
    const float s = wgt[gq] * inv;
#pragma unroll
    for (int e = 0; e < 4; ++e) o[e] += (float)p[e] * s;
  }
  f32x4 ov = {o[0], o[1], o[2], o[3]};
  *(f32x4*)(Out + base) = ov;
}

// ---------------- K3 fallback (r6 form, skewed-Srel gather), for small ws.
#define NIT 32
__global__ __launch_bounds__(512, 2) void k3_attn(
    const f16* __restrict__ Qh, const f16* __restrict__ Kh, const f16* __restrict__ Vh,
    const f16* __restrict__ QEh, float* __restrict__ Out) {
  extern __shared__ char smemd[];  // 73728 B
  const int b = blockIdx.y;
  const int q0 = blockIdx.x * 64;
  const int tid = threadIdx.x, lane = tid & 63, w = tid >> 6;
  const int g = w >> 2, wq = w & 3;
  const int qw = q0 + wq * 16;
  const int lt = tid & 255;
  const int gi = lane >> 4;

  float* Cst = (float*)smemd;
  float* ml = (float*)(smemd + 65536);

  const f16* Qb = Qh + (size_t)b * NL * ND;
  const f16* Kb = Kh + (size_t)b * NL * ND;
  const f16* Vb = Vh + (size_t)b * NL * ND;
  const f16* QEb = QEh + (size_t)b * NL * NL;  // skewed Srel layout

  f16x8 qf[8];
  {
    const int r = qw + (lane & 15);
#pragma unroll
    for (int kk = 0; kk < 8; ++kk)
      qf[kk] = *(const f16x8*)(Qb + (size_t)r * ND + kk * 32 + gi * 8);
  }

  f32x4 acc[16];
#pragma unroll
  for (int i = 0; i < 16; ++i) acc[i] = f32x4{0.f, 0.f, 0.f, 0.f};
  float mrun = -1e30f, lrun = 0.f;

  f16x8 kst[4], vst[4];
  const int kp = lt & 15, dch = lt >> 4;

  auto stage_load = [&](int t) {
    const f16* Ks = Kb + (size_t)(g * NIT + t) * 32 * ND;
#pragma unroll
    for (int j = 0; j < 4; ++j) {
      const int c = j * 256 + lt;
      kst[j] = *(const f16x8*)(Ks + (c >> 5) * ND + (c & 31) * 8);
    }
    const f16* Vs = Vb + (size_t)(g * NIT + t) * 32 * ND;
    vst[0] = *(const f16x8*)(Vs + (2 * kp) * ND + dch * 16);
    vst[1] = *(const f16x8*)(Vs + (2 * kp) * ND + dch * 16 + 8);
    vst[2] = *(const f16x8*)(Vs + (2 * kp + 1) * ND + dch * 16);
    vst[3] = *(const f16x8*)(Vs + (2 * kp + 1) * ND + dch * 16 + 8);
  };
  auto stage_write = [&]() {
    char* Kld = smemd + g * KVBUF;
    char* Vld = Kld + 16384;
#pragma unroll
    for (int j = 0; j < 4; ++j) {
      const int c = j * 256 + lt;
      const int key = c >> 5, d0 = (c & 31) * 16;
      *(f16x8*)(Kld + key * 512 + (d0 ^ ((key & 7) << 4))) = kst[j];
    }
#pragma unroll
    for (int jj = 0; jj < 16; ++jj) {
      f16x2 pr;
      pr.x = (jj < 8) ? vst[0][jj & 7] : vst[1][jj & 7];
      pr.y = (jj < 8) ? vst[2][jj & 7] : vst[3][jj & 7];
      *(f16x2*)(Vld + (dch * 16 + jj) * 80 + kp * 4) = pr;
    }
  };

  stage_load(0);
  stage_write();
  __syncthreads();

  const int qa = qw + (lane & 15);

  for (int t = 0; t < NIT; ++t) {
    const int k0 = (g * NIT + t) * 32;

    float srel[2][4];
#pragma unroll
    for (int nt = 0; nt < 2; ++nt) {
      const int kb2 = k0 + nt * 16 + gi * 4;
      f16x4 v4 = *(const f16x4*)(QEb + (size_t)qa * NL + kb2);
#pragma unroll
      for (int j = 0; j < 4; ++j)
        srel[nt][j] = (kb2 + j == qa + 1) ? 0.f : (float)v4[j];
    }

    if (t < NIT - 1) stage_load(t + 1);

    const char* Kld = smemd + g * KVBUF;
    const char* Vld = Kld + 16384;

    f32x4 s[2] = {f32x4{0.f, 0.f, 0.f, 0.f}, f32x4{0.f, 0.f, 0.f, 0.f}};
#pragma unroll
    for (int kk = 0; kk < 8; ++kk) {
      const int ko = kk * 64 + gi * 16;
#pragma unroll
      for (int nt = 0; nt < 2; ++nt) {
        const int key = nt * 16 + (lane & 15);
        f16x8 af = *(const f16x8*)(Kld + key * 512 + (ko ^ ((key & 7) << 4)));
        s[nt] = mfma16(af, qf[kk], s[nt]);
      }
    }

    float sv[2][4];
#pragma unroll
    for (int nt = 0; nt < 2; ++nt)
#pragma unroll
      for (int j = 0; j < 4; ++j) sv[nt][j] = 0.0625f * (s[nt][j] + srel[nt][j]);

    float pm = fmaxf(fmaxf(fmaxf(sv[0][0], sv[0][1]), fmaxf(sv[0][2], sv[0][3])),
                     fmaxf(fmaxf(sv[1][0], sv[1][1]), fmaxf(sv[1][2], sv[1][3])));
    pm = fmaxf(pm, __shfl_xor(pm, 16, 64));
    pm = fmaxf(pm, __shfl_xor(pm, 32, 64));

    float p[2][4];
    if (__any(pm > mrun + 8.f)) {
      const float mn = fmaxf(mrun, pm);
      const float al = __expf(mrun - mn);
      mrun = mn;
#pragma unroll
      for (int nt = 0; nt < 2; ++nt)
#pragma unroll
        for (int j = 0; j < 4; ++j) p[nt][j] = __expf(sv[nt][j] - mrun);
      float rs = (p[0][0] + p[0][1]) + (p[0][2] + p[0][3]) +
                 (p[1][0] + p[1][1]) + (p[1][2] + p[1][3]);
      rs += __shfl_xor(rs, 16, 64);
      rs += __shfl_xor(rs, 32, 64);
      lrun = lrun * al + rs;
#pragma unroll
      for (int j = 0; j < 4; ++j) {
        const float aj = __shfl(al, gi * 4 + j, 16);
#pragma unroll
        for (int dt = 0; dt < 16; ++dt) acc[dt][j] *= aj;
      }
    } else {
#pragma unroll
      for (int nt = 0; nt < 2; ++nt)
#pragma unroll
        for (int j = 0; j < 4; ++j) p[nt][j] = __expf(sv[nt][j] - mrun);
      float rs = (p[0][0] + p[0][1]) + (p[0][2] + p[0][3]) +
                 (p[1][0] + p[1][1]) + (p[1][2] + p[1][3]);
      rs += __shfl_xor(rs, 16, 64);
      rs += __shfl_xor(rs, 32, 64);
      lrun += rs;
    }

    union {
      fp16x2 h2[2];
      f16x4 h4;
    } pu0, pu1;
    pu0.h2[0] = __builtin_amdgcn_cvt_pkrtz(p[0][0], p[0][1]);
    pu0.h2[1] = __builtin_amdgcn_cvt_pkrtz(p[0][2], p[0][3]);
    pu1.h2[0] = __builtin_amdgcn_cvt_pkrtz(p[1][0], p[1][1]);
    pu1.h2[1] = __builtin_amdgcn_cvt_pkrtz(p[1][2], p[1][3]);

#pragma unroll
    for (int dt = 0; dt < 16; ++dt) {
      const char* vrow = Vld + (dt * 16 + (lane & 15)) * 80 + 8 * gi;
      f16x4 v0 = *(const f16x4*)(vrow);
      f16x4 v1 = *(const f16x4*)(vrow + 32);
      acc[dt] = __builtin_amdgcn_mfma_f32_16x16x16f16(pu0.h4, v0, acc[dt], 0, 0, 0);
      acc[dt] = __builtin_amdgcn_mfma_f32_16x16x16f16(pu1.h4, v1, acc[dt], 0, 0, 0);
    }

    __syncthreads();
    if (t < NIT - 1) stage_write();
    __syncthreads();
  }

  if (g == 1) {
#pragma unroll
    for (int dt = 0; dt < 16; ++dt)
#pragma unroll
      for (int j = 0; j < 4; ++j)
        Cst[wq * 4096 + (gi * 4 + j) * 256 + dt * 16 + (lane & 15)] = acc[dt][j];
    if (lane < 16) {
      ml[(wq * 16 + lane) * 2 + 0] = mrun;
      ml[(wq * 16 + lane) * 2 + 1] = lrun;
    }
  }
  __syncthreads();
  if (g == 0) {
    float* Ob = Out + (size_t)b * NL * ND;
#pragma unroll
    for (int j = 0; j < 4; ++j) {
      const int rloc = gi * 4 + j;
      const float m0r = __shfl(mrun, rloc, 16);
      const float l0r = __shfl(lrun, rloc, 16);
      const float m1 = ml[(wq * 16 + rloc) * 2 + 0];
      const float l1 = ml[(wq * 16 + rloc) * 2 + 1];
      const float M = fmaxf(m0r, m1);
      const float c0 = __expf(m0r - M), c1 = __expf(m1 - M);
      const float inv = 1.f / (l0r * c0 + l1 * c1);
      const int row = qw + rloc;
#pragma unroll
      for (int dt = 0; dt < 16; ++dt) {
        const float o1 = Cst[wq * 4096 + rloc * 256 + dt * 16 + (lane & 15)];
        Ob[(size_t)row * ND + dt * 16 + (lane & 15)] = (acc[dt][j] * c0 + o1 * c1) * inv;
      }
    }
  }
}

extern "C" void kernel_launch(void* const* d_in, const int* in_sizes, int n_in,
                              void* d_out, int out_size, void* d_ws, size_t ws_size,
                              hipStream_t stream) {
  (void)in_sizes; (void)n_in; (void)out_size;
  const float* inQ = (const float*)d_in[0];
  const float* inK = (const float*)d_in[1];
  const float* inV = (const float*)d_in[2];
  const float* Wq = (const float*)d_in[3];
  const float* Wk = (const float*)d_in[4];
  const float* Wv = (const float*)d_in[5];
  float* out = (float*)d_out;

  // ws layout (f16): Qh,Kh,Vh [B*L*D]; WT [3*256*256]; QEh [B*L*L] (SKEWED);
  // Pac f16 [NGRP][B*L][D]; then (f32) Pml [NGRP][B*L][2].
  f16* ws = (f16*)d_ws;
  f16* Qh = ws;
  f16* Kh = Qh + (size_t)QKV_ELEMS;
  f16* Vh = Kh + (size_t)QKV_ELEMS;
  f16* WT = Vh + (size_t)QKV_ELEMS;
  f16* QEh = WT + 3 * 65536;
  f16* Pac = QEh + (size_t)NB * NL * NL;
  float* Pml = (float*)(Pac + (size_t)NGRP * QKV_ELEMS);
  const size_t need = (size_t)((char*)(Pml + NGRP * NB * NL * 2) - (char*)d_ws);

  k0_wt<<<dim3(768), dim3(256), 0, stream>>>(Wq, Wk, Wv, WT);
  k1_proj<<<dim3(256, 3), dim3(256), 0, stream>>>(inQ, inK, inV, WT, Qh, Kh, Vh);
  k2_qe<<<dim3(16, 16, 8), dim3(256), 0, stream>>>(Qh, Kh, QEh);
  if (ws_size >= need) {
    k3_part<<<dim3(32, 8, NGRP), dim3(256), 0, stream>>>(Qh, Kh, Vh, QEh, Pac, Pml);
    k4_comb<<<dim3(NB * NL / 4), dim3(256), 0, stream>>>(Pac, Pml, out);
  } else {
    k3_attn<<<dim3(32, 8), dim3(512), 73728, stream>>>(Qh, Kh, Vh, QEh, out);
  }
}